// Round 8
// baseline (64.864 us; speedup 1.0000x reference)
//
#include <hip/hip_runtime.h>

// LDDMM variational evolve: N-body Gaussian kernel sums, N=8192, D=3, fp32.
// dmom_i = (1/SIG2) * sum_j K_ij * <mom_i,mom_j> * (pos_i - pos_j)
// dpos_i = sum_j K_ij * mom_j
// K_ij = exp(-||xi-xj||^2/(2*SIG2)), SIG2=0.01 -> exp2(-72.1348*d2)
//
// Cell list (R6 insight): K < 4e-6 for d2 > 0.25 (x ~ N(0,1)); dropped-pair
// RMS error ~3e-3 << threshold 2.36. Edge 0.5, 16^3 grid: 67.1M -> ~4.5M
// pair evals. Pipeline: memset -> hist -> scan -> scatter -> main.
// R7 NaN lesson: ci MUST stay inside the exponent. arg = ci + A_DOT<xi,xj>
// + A_R*rj2 = -72.13*d2 <= 0 always; folding exp2(ci) outside lets the
// inner exp2 overflow to inf (xi~xj, |x|~3 -> arg ~ +650), inf*0 = NaN.
// exp = __builtin_amdgcn_exp2f (plain exp2f -> OCML fixup path; R2 measured).

#define NPTS  8192
#define NC    16
#define NCELL (NC * NC * NC)   // 4096
#define ORIGIN   (-4.0f)
#define INV_EDGE 2.0f          // edge 0.5

#define A_DOT 144.269504088896f     // 2*50*log2(e)
#define A_R   (-72.134752044448f)   // -50*log2(e)
#define INV_SIG2 100.0f

#define EXP2(x) __builtin_amdgcn_exp2f(x)

__device__ __forceinline__ int cell_of(float x, float y, float z) {
    int cx = (int)floorf((x - ORIGIN) * INV_EDGE);
    int cy = (int)floorf((y - ORIGIN) * INV_EDGE);
    int cz = (int)floorf((z - ORIGIN) * INV_EDGE);
    cx = min(max(cx, 0), NC - 1);
    cy = min(max(cy, 0), NC - 1);
    cz = min(max(cz, 0), NC - 1);
    return (cx * NC + cy) * NC + cz;
}

__global__ __launch_bounds__(256)
void k_hist(const float* __restrict__ pos,
            int* __restrict__ cellid, int* __restrict__ rank,
            int* __restrict__ count)
{
    const int i = blockIdx.x * 256 + threadIdx.x;
    const float x = pos[3*i+0], y = pos[3*i+1], z = pos[3*i+2];
    const int c = cell_of(x, y, z);
    cellid[i] = c;
    rank[i] = atomicAdd(&count[c], 1);
}

// Exclusive prefix over NCELL counts, one block of 256 threads x 16 cells.
__global__ __launch_bounds__(256)
void k_scan(const int* __restrict__ count, int* __restrict__ start)
{
    __shared__ int sums[256];
    const int t = threadIdx.x;
    int loc[16];
    int s = 0;
    #pragma unroll
    for (int k = 0; k < 16; ++k) { loc[k] = s; s += count[t * 16 + k]; }
    sums[t] = s;
    __syncthreads();
    #pragma unroll
    for (int off = 1; off < 256; off <<= 1) {
        const int v = (t >= off) ? sums[t - off] : 0;
        __syncthreads();
        sums[t] += v;
        __syncthreads();
    }
    const int pre = (t == 0) ? 0 : sums[t - 1];
    #pragma unroll
    for (int k = 0; k < 16; ++k) start[t * 16 + k] = pre + loc[k];
    if (t == 255) start[NCELL] = pre + s;   // == NPTS
}

__global__ __launch_bounds__(256)
void k_scatter(const float* __restrict__ mom, const float* __restrict__ pos,
               const int* __restrict__ cellid, const int* __restrict__ rank,
               const int* __restrict__ start,
               float* __restrict__ pm, int* __restrict__ inv)
{
    const int i = blockIdx.x * 256 + threadIdx.x;
    const int dst = start[cellid[i]] + rank[i];
    const float x = pos[3*i+0], y = pos[3*i+1], z = pos[3*i+2];
    const float r2 = x*x + y*y + z*z;
    float4* v = reinterpret_cast<float4*>(pm + (size_t)8 * dst);
    v[0] = make_float4(A_DOT*x, A_DOT*y, A_DOT*z, A_R*r2);
    v[1] = make_float4(mom[3*i+0], mom[3*i+1], mom[3*i+2], 0.0f);
    inv[dst] = i;
}

// 8 threads per sorted point; thread k covers stencil cells k, k+8, k+16, k+24.
__global__ __launch_bounds__(256)
void k_main(const float* __restrict__ mom, const float* __restrict__ pos,
            const float* __restrict__ pm, const int* __restrict__ inv,
            const int* __restrict__ start, float* __restrict__ out)
{
    const int tid = blockIdx.x * 256 + threadIdx.x;
    const int si = tid >> 3;        // sorted index
    const int k  = tid & 7;

    const int oi = inv[si];
    const float xi = pos[3*oi+0], yi = pos[3*oi+1], zi = pos[3*oi+2];
    const float pxi = mom[3*oi+0], pyi = mom[3*oi+1], pzi = mom[3*oi+2];
    const float ci  = A_R * (xi*xi + yi*yi + zi*zi);

    int cx = (int)floorf((xi - ORIGIN) * INV_EDGE);
    int cy = (int)floorf((yi - ORIGIN) * INV_EDGE);
    int cz = (int)floorf((zi - ORIGIN) * INV_EDGE);
    cx = min(max(cx, 0), NC - 1);
    cy = min(max(cy, 0), NC - 1);
    cz = min(max(cz, 0), NC - 1);

    float S = 0.f, SPx = 0.f, SPy = 0.f, SPz = 0.f;
    float apx = 0.f, apy = 0.f, apz = 0.f;

    for (int sidx = k; sidx < 27; sidx += 8) {
        const int dx = sidx / 9 - 1;
        const int dy = (sidx / 3) % 3 - 1;
        const int dz = sidx % 3 - 1;
        const int nx = cx + dx, ny = cy + dy, nz = cz + dz;
        if (nx < 0 || nx >= NC || ny < 0 || ny >= NC || nz < 0 || nz >= NC)
            continue;
        const int c = (nx * NC + ny) * NC + nz;
        const int st = start[c], en = start[c + 1];
        for (int j = st; j < en; ++j) {
            const float4* jr = reinterpret_cast<const float4*>(pm + (size_t)8 * j);
            const float4 P = jr[0];
            const float4 M = jr[1];
            // arg = ci + A_DOT*<xi,xj> + A_R*rj2 = -72.13*d2 <= 0 (no overflow)
            float arg = __builtin_fmaf(zi, P.z, ci + P.w);
            arg = __builtin_fmaf(yi, P.y, arg);
            arg = __builtin_fmaf(xi, P.x, arg);
            const float K = EXP2(arg);
            const float C = __builtin_fmaf(pzi, M.z,
                              __builtin_fmaf(pyi, M.y, pxi * M.x));
            const float s = K * C;
            S += s;
            SPx = __builtin_fmaf(s, P.x, SPx);
            SPy = __builtin_fmaf(s, P.y, SPy);
            SPz = __builtin_fmaf(s, P.z, SPz);
            apx = __builtin_fmaf(K, M.x, apx);
            apy = __builtin_fmaf(K, M.y, apy);
            apz = __builtin_fmaf(K, M.z, apz);
        }
    }

    // Reduce the 8 stencil-split lanes (consecutive lanes, same wave).
    #pragma unroll
    for (int off = 1; off < 8; off <<= 1) {
        S   += __shfl_xor(S,   off);
        SPx += __shfl_xor(SPx, off);
        SPy += __shfl_xor(SPy, off);
        SPz += __shfl_xor(SPz, off);
        apx += __shfl_xor(apx, off);
        apy += __shfl_xor(apy, off);
        apz += __shfl_xor(apz, off);
    }

    if (k == 0) {
        const float us = INV_SIG2 / A_DOT;
        out[3*oi+0] = INV_SIG2 * xi * S - us * SPx;
        out[3*oi+1] = INV_SIG2 * yi * S - us * SPy;
        out[3*oi+2] = INV_SIG2 * zi * S - us * SPz;
        out[3*NPTS + 3*oi+0] = apx;
        out[3*NPTS + 3*oi+1] = apy;
        out[3*NPTS + 3*oi+2] = apz;
    }
}

extern "C" void kernel_launch(void* const* d_in, const int* in_sizes, int n_in,
                              void* d_out, int out_size, void* d_ws, size_t ws_size,
                              hipStream_t stream)
{
    const float* mom = (const float*)d_in[0];
    const float* pos = (const float*)d_in[1];
    float* out = (float*)d_out;

    // ws layout: pm (8*NPTS f), inv, cellid, rank (NPTS i each),
    //            count (NCELL i), start (NCELL+1 i)  -> ~385 KB total.
    float* pm   = (float*)d_ws;
    int* inv    = (int*)(pm + (size_t)8 * NPTS);
    int* cellid = inv + NPTS;
    int* rank   = cellid + NPTS;
    int* count  = rank + NPTS;
    int* start  = count + NCELL;

    hipMemsetAsync(count, 0, NCELL * sizeof(int), stream);
    k_hist<<<NPTS / 256, 256, 0, stream>>>(pos, cellid, rank, count);
    k_scan<<<1, 256, 0, stream>>>(count, start);
    k_scatter<<<NPTS / 256, 256, 0, stream>>>(mom, pos, cellid, rank, start, pm, inv);
    k_main<<<(8 * NPTS) / 256, 256, 0, stream>>>(mom, pos, pm, inv, start, out);
}

// Round 9
// 36.500 us; speedup vs baseline: 1.7771x; 1.7771x over previous
//
#include <hip/hip_runtime.h>

// LDDMM variational evolve: N-body Gaussian kernel sums, N=8192, D=3, fp32.
// dmom_i = (1/SIG2) * sum_j K_ij * <mom_i,mom_j> * (pos_i - pos_j)
// dpos_i = sum_j K_ij * mom_j
// K_ij = exp(-||xi-xj||^2/(2*SIG2)), SIG2=0.01 -> exp2(-72.1348*d2)
//
// Cell list: K < 4e-6 for d2 > 0.25 (x ~ N(0,1)); dropped-pair RMS error
// ~3e-3 << threshold 2.36. Edge 0.5, 16^3 grid: 67.1M -> ~4.5M pair evals.
// R8 lesson: thread-serial j-loops + 256-block grid = load-imbalance death
// (k_main 48us, VALUBusy 8%, central cells ~63 pts). R9: WAVE-PER-POINT --
// lanes 0-26 prefetch all stencil (st,en) in parallel, inner loop is
// lane-parallel coalesced over cell members, 64-lane butterfly reduce.
// R7 NaN lesson: ci stays inside the exponent (arg <= 0 always).
// exp = __builtin_amdgcn_exp2f (plain exp2f -> OCML fixup; R2 measured).

#define NPTS  8192
#define NC    16
#define NCELL (NC * NC * NC)   // 4096
#define ORIGIN   (-4.0f)
#define INV_EDGE 2.0f          // edge 0.5

#define A_DOT 144.269504088896f     // 2*50*log2(e)
#define A_R   (-72.134752044448f)   // -50*log2(e)
#define INV_SIG2 100.0f

#define EXP2(x) __builtin_amdgcn_exp2f(x)

__device__ __forceinline__ int clampc(int c) { return min(max(c, 0), NC - 1); }

__global__ __launch_bounds__(256)
void k_hist(const float* __restrict__ pos,
            int* __restrict__ cellid, int* __restrict__ rank,
            int* __restrict__ count)
{
    const int i = blockIdx.x * 256 + threadIdx.x;
    const float x = pos[3*i+0], y = pos[3*i+1], z = pos[3*i+2];
    const int cx = clampc((int)floorf((x - ORIGIN) * INV_EDGE));
    const int cy = clampc((int)floorf((y - ORIGIN) * INV_EDGE));
    const int cz = clampc((int)floorf((z - ORIGIN) * INV_EDGE));
    const int c = (cx * NC + cy) * NC + cz;
    cellid[i] = c;
    rank[i] = atomicAdd(&count[c], 1);
}

// Exclusive prefix over NCELL counts, one block of 256 threads x 16 cells.
__global__ __launch_bounds__(256)
void k_scan(const int* __restrict__ count, int* __restrict__ start)
{
    __shared__ int sums[256];
    const int t = threadIdx.x;
    int loc[16];
    int s = 0;
    #pragma unroll
    for (int k = 0; k < 16; ++k) { loc[k] = s; s += count[t * 16 + k]; }
    sums[t] = s;
    __syncthreads();
    #pragma unroll
    for (int off = 1; off < 256; off <<= 1) {
        const int v = (t >= off) ? sums[t - off] : 0;
        __syncthreads();
        sums[t] += v;
        __syncthreads();
    }
    const int pre = (t == 0) ? 0 : sums[t - 1];
    #pragma unroll
    for (int k = 0; k < 16; ++k) start[t * 16 + k] = pre + loc[k];
    if (t == 255) start[NCELL] = pre + s;   // == NPTS
}

__global__ __launch_bounds__(256)
void k_scatter(const float* __restrict__ mom, const float* __restrict__ pos,
               const int* __restrict__ cellid, const int* __restrict__ rank,
               const int* __restrict__ start,
               float* __restrict__ pmP, float* __restrict__ pmM,
               int* __restrict__ inv)
{
    const int i = blockIdx.x * 256 + threadIdx.x;
    const int dst = start[cellid[i]] + rank[i];
    const float x = pos[3*i+0], y = pos[3*i+1], z = pos[3*i+2];
    const float r2 = x*x + y*y + z*z;
    reinterpret_cast<float4*>(pmP)[dst] = make_float4(A_DOT*x, A_DOT*y, A_DOT*z, A_R*r2);
    reinterpret_cast<float4*>(pmM)[dst] = make_float4(mom[3*i+0], mom[3*i+1], mom[3*i+2], 0.0f);
    inv[dst] = i;
}

// One 64-lane wave per sorted point. Lanes 0..26 prefetch stencil (st,en);
// inner loop lane-parallel over cell members (coalesced float4 loads).
__global__ __launch_bounds__(256)
void k_main(const float* __restrict__ mom, const float* __restrict__ pos,
            const float* __restrict__ pmP, const float* __restrict__ pmM,
            const int* __restrict__ inv, const int* __restrict__ start,
            float* __restrict__ out)
{
    const int wid  = (blockIdx.x * 256 + threadIdx.x) >> 6;   // sorted point idx
    const int lane = threadIdx.x & 63;

    const int oi = inv[wid];                    // wave-uniform
    const float xi = pos[3*oi+0], yi = pos[3*oi+1], zi = pos[3*oi+2];
    const float pxi = mom[3*oi+0], pyi = mom[3*oi+1], pzi = mom[3*oi+2];
    const float ci  = A_R * (xi*xi + yi*yi + zi*zi);

    const int cx = clampc((int)floorf((xi - ORIGIN) * INV_EDGE));
    const int cy = clampc((int)floorf((yi - ORIGIN) * INV_EDGE));
    const int cz = clampc((int)floorf((zi - ORIGIN) * INV_EDGE));

    // Lanes 0..26: load this stencil cell's range in parallel.
    int st_l = 0, en_l = 0;
    if (lane < 27) {
        const int dx = lane / 9 - 1;
        const int dy = (lane / 3) % 3 - 1;
        const int dz = lane % 3 - 1;
        const int nx = cx + dx, ny = cy + dy, nz = cz + dz;
        if (nx >= 0 && nx < NC && ny >= 0 && ny < NC && nz >= 0 && nz < NC) {
            const int c = (nx * NC + ny) * NC + nz;
            st_l = start[c];
            en_l = start[c + 1];
        }
    }

    float S = 0.f, SPx = 0.f, SPy = 0.f, SPz = 0.f;
    float apx = 0.f, apy = 0.f, apz = 0.f;

    #pragma unroll 1
    for (int sidx = 0; sidx < 27; ++sidx) {
        const int st = __shfl(st_l, sidx);      // uniform src -> readlane
        const int en = __shfl(en_l, sidx);
        for (int j = st + lane; j < en; j += 64) {
            const float4 P = reinterpret_cast<const float4*>(pmP)[j];
            const float4 M = reinterpret_cast<const float4*>(pmM)[j];
            // arg = ci + A_DOT*<xi,xj> + A_R*rj2 = -72.13*d2 <= 0 (no overflow)
            float arg = __builtin_fmaf(zi, P.z, ci + P.w);
            arg = __builtin_fmaf(yi, P.y, arg);
            arg = __builtin_fmaf(xi, P.x, arg);
            const float K = EXP2(arg);
            const float C = __builtin_fmaf(pzi, M.z,
                              __builtin_fmaf(pyi, M.y, pxi * M.x));
            const float s = K * C;
            S += s;
            SPx = __builtin_fmaf(s, P.x, SPx);
            SPy = __builtin_fmaf(s, P.y, SPy);
            SPz = __builtin_fmaf(s, P.z, SPz);
            apx = __builtin_fmaf(K, M.x, apx);
            apy = __builtin_fmaf(K, M.y, apy);
            apz = __builtin_fmaf(K, M.z, apz);
        }
    }

    // 64-lane butterfly reduce of the 7 accumulators.
    #pragma unroll
    for (int off = 1; off < 64; off <<= 1) {
        S   += __shfl_xor(S,   off);
        SPx += __shfl_xor(SPx, off);
        SPy += __shfl_xor(SPy, off);
        SPz += __shfl_xor(SPz, off);
        apx += __shfl_xor(apx, off);
        apy += __shfl_xor(apy, off);
        apz += __shfl_xor(apz, off);
    }

    if (lane == 0) {
        const float us = INV_SIG2 / A_DOT;
        out[3*oi+0] = INV_SIG2 * xi * S - us * SPx;
        out[3*oi+1] = INV_SIG2 * yi * S - us * SPy;
        out[3*oi+2] = INV_SIG2 * zi * S - us * SPz;
        out[3*NPTS + 3*oi+0] = apx;
        out[3*NPTS + 3*oi+1] = apy;
        out[3*NPTS + 3*oi+2] = apz;
    }
}

extern "C" void kernel_launch(void* const* d_in, const int* in_sizes, int n_in,
                              void* d_out, int out_size, void* d_ws, size_t ws_size,
                              hipStream_t stream)
{
    const float* mom = (const float*)d_in[0];
    const float* pos = (const float*)d_in[1];
    float* out = (float*)d_out;

    // ws layout: pmP (4*NPTS f), pmM (4*NPTS f), inv, cellid, rank (NPTS i),
    //            count (NCELL i), start (NCELL+1 i)  -> ~385 KB total.
    float* pmP  = (float*)d_ws;
    float* pmM  = pmP + (size_t)4 * NPTS;
    int* inv    = (int*)(pmM + (size_t)4 * NPTS);
    int* cellid = inv + NPTS;
    int* rank   = cellid + NPTS;
    int* count  = rank + NPTS;
    int* start  = count + NCELL;

    hipMemsetAsync(count, 0, NCELL * sizeof(int), stream);
    k_hist<<<NPTS / 256, 256, 0, stream>>>(pos, cellid, rank, count);
    k_scan<<<1, 256, 0, stream>>>(count, start);
    k_scatter<<<NPTS / 256, 256, 0, stream>>>(mom, pos, cellid, rank, start, pmP, pmM, inv);
    k_main<<<(64 * NPTS) / 256, 256, 0, stream>>>(mom, pos, pmP, pmM, inv, start, out);
}

// Round 10
// 34.953 us; speedup vs baseline: 1.8557x; 1.0442x over previous
//
#include <hip/hip_runtime.h>

// LDDMM variational evolve: N-body Gaussian kernel sums, N=8192, D=3, fp32.
// dmom_i = (1/SIG2) * sum_j K_ij * <mom_i,mom_j> * (pos_i - pos_j)
// dpos_i = sum_j K_ij * mom_j
// K_ij = exp(-||xi-xj||^2/(2*SIG2)), SIG2=0.01 -> exp2(-72.1348*d2)
//
// Cell list: K < 4e-6 for d2 > 0.25 (x ~ N(0,1)); dropped-pair RMS error
// ~3e-3 << threshold 2.36. Edge 0.5, 16^3 grid: 67.1M -> ~4.5M pair evals.
// Ladder: R8 thread-serial = imbalance death (48us). R9 wave-per-point =
// ~20us main + ~16us 5-dispatch prep. R10: (1) prep fused to ONE single-block
// kernel (LDS hist+scan+scatter); (2) z-merge: 27 stencil cells = 9
// CONTIGUOUS sorted ranges (cells (nx,ny,lz..hz) adjacent in memory);
// (3) 2 points/wave share every loaded j-record (loads halve; union-range
// extra evals only add accuracy since K~0).
// R7 NaN lesson: ci stays inside the exponent (arg <= 0 always).
// exp = __builtin_amdgcn_exp2f (plain exp2f -> OCML fixup; R2 measured).

#define NPTS  8192
#define NC    16
#define NCELL (NC * NC * NC)   // 4096
#define ORIGIN   (-4.0f)
#define INV_EDGE 2.0f          // edge 0.5

#define A_DOT 144.269504088896f     // 2*50*log2(e)
#define A_R   (-72.134752044448f)   // -50*log2(e)
#define INV_SIG2 100.0f

#define EXP2(x) __builtin_amdgcn_exp2f(x)

__device__ __forceinline__ int clampc(int c) { return min(max(c, 0), NC - 1); }

// ---------------- fused prep: hist + scan + scatter, one block ----------------
__global__ __launch_bounds__(1024)
void k_prep(const float* __restrict__ mom, const float* __restrict__ pos,
            float* __restrict__ pmP, float* __restrict__ pmM,
            int* __restrict__ inv, int* __restrict__ start_g)
{
    __shared__ int cnt[NCELL];    // counts, then exclusive starts
    __shared__ int tsum[1024];
    const int t = threadIdx.x;

    #pragma unroll
    for (int k = 0; k < NCELL / 1024; ++k) cnt[t + k * 1024] = 0;
    __syncthreads();

    // phase 1: histogram (8 points per thread, coalesced stride)
    int cid[8], rnk[8];
    #pragma unroll
    for (int k = 0; k < 8; ++k) {
        const int i = t + k * 1024;
        const float x = pos[3*i+0], y = pos[3*i+1], z = pos[3*i+2];
        const int cx = clampc((int)floorf((x - ORIGIN) * INV_EDGE));
        const int cy = clampc((int)floorf((y - ORIGIN) * INV_EDGE));
        const int cz = clampc((int)floorf((z - ORIGIN) * INV_EDGE));
        cid[k] = (cx * NC + cy) * NC + cz;
        rnk[k] = atomicAdd(&cnt[cid[k]], 1);
    }
    __syncthreads();

    // phase 2: exclusive scan of 4096 counts (4 cells/thread + log-scan)
    int loc[4];
    int s = 0;
    #pragma unroll
    for (int k = 0; k < 4; ++k) { loc[k] = s; s += cnt[t * 4 + k]; }
    tsum[t] = s;
    __syncthreads();
    for (int off = 1; off < 1024; off <<= 1) {
        const int v = (t >= off) ? tsum[t - off] : 0;
        __syncthreads();
        tsum[t] += v;
        __syncthreads();
    }
    const int pre = (t == 0) ? 0 : tsum[t - 1];
    #pragma unroll
    for (int k = 0; k < 4; ++k) {
        const int c = t * 4 + k;
        const int st = pre + loc[k];
        start_g[c] = st;
    }
    if (t == 1023) start_g[NCELL] = pre + s;   // == NPTS
    __syncthreads();
    #pragma unroll
    for (int k = 0; k < 4; ++k) cnt[t * 4 + k] = pre + loc[k];  // cnt := start
    __syncthreads();

    // phase 3: scatter packed records
    #pragma unroll
    for (int k = 0; k < 8; ++k) {
        const int i = t + k * 1024;
        const int dst = cnt[cid[k]] + rnk[k];
        const float x = pos[3*i+0], y = pos[3*i+1], z = pos[3*i+2];
        const float r2 = x*x + y*y + z*z;
        reinterpret_cast<float4*>(pmP)[dst] =
            make_float4(A_DOT*x, A_DOT*y, A_DOT*z, A_R*r2);
        reinterpret_cast<float4*>(pmM)[dst] =
            make_float4(mom[3*i+0], mom[3*i+1], mom[3*i+2], 0.0f);
        inv[dst] = i;
    }
}

// ---------------- main: one wave per 2 sorted points ----------------
__device__ __forceinline__ void eval_one(
    const float4 P, const float4 M,
    const float xi, const float yi, const float zi, const float ci,
    const float pxi, const float pyi, const float pzi,
    float& S, float& SPx, float& SPy, float& SPz,
    float& apx, float& apy, float& apz)
{
    // arg = ci + A_DOT*<xi,xj> + A_R*rj2 = -72.13*d2 <= 0 (no overflow)
    float arg = __builtin_fmaf(zi, P.z, ci + P.w);
    arg = __builtin_fmaf(yi, P.y, arg);
    arg = __builtin_fmaf(xi, P.x, arg);
    const float K = EXP2(arg);
    const float C = __builtin_fmaf(pzi, M.z, __builtin_fmaf(pyi, M.y, pxi * M.x));
    const float s = K * C;
    S += s;
    SPx = __builtin_fmaf(s, P.x, SPx);
    SPy = __builtin_fmaf(s, P.y, SPy);
    SPz = __builtin_fmaf(s, P.z, SPz);
    apx = __builtin_fmaf(K, M.x, apx);
    apy = __builtin_fmaf(K, M.y, apy);
    apz = __builtin_fmaf(K, M.z, apz);
}

__global__ __launch_bounds__(256)
void k_main(const float* __restrict__ mom, const float* __restrict__ pos,
            const float* __restrict__ pmP, const float* __restrict__ pmM,
            const int* __restrict__ inv, const int* __restrict__ start,
            float* __restrict__ out)
{
    const int wid  = (blockIdx.x * 256 + threadIdx.x) >> 6;   // 0..4095
    const int lane = threadIdx.x & 63;
    const int si0 = 2 * wid, si1 = 2 * wid + 1;

    const int oi0 = inv[si0], oi1 = inv[si1];                 // wave-uniform
    const float x0 = pos[3*oi0+0], y0 = pos[3*oi0+1], z0 = pos[3*oi0+2];
    const float px0 = mom[3*oi0+0], py0 = mom[3*oi0+1], pz0 = mom[3*oi0+2];
    const float x1 = pos[3*oi1+0], y1 = pos[3*oi1+1], z1 = pos[3*oi1+2];
    const float px1 = mom[3*oi1+0], py1 = mom[3*oi1+1], pz1 = mom[3*oi1+2];
    const float c0 = A_R * (x0*x0 + y0*y0 + z0*z0);
    const float c1 = A_R * (x1*x1 + y1*y1 + z1*z1);

    const int cx0 = clampc((int)floorf((x0 - ORIGIN) * INV_EDGE));
    const int cy0 = clampc((int)floorf((y0 - ORIGIN) * INV_EDGE));
    const int cz0 = clampc((int)floorf((z0 - ORIGIN) * INV_EDGE));
    const int cx1 = clampc((int)floorf((x1 - ORIGIN) * INV_EDGE));
    const int cy1 = clampc((int)floorf((y1 - ORIGIN) * INV_EDGE));
    const int cz1 = clampc((int)floorf((z1 - ORIGIN) * INV_EDGE));

    float S0=0.f, SP0x=0.f, SP0y=0.f, SP0z=0.f, ap0x=0.f, ap0y=0.f, ap0z=0.f;
    float S1=0.f, SP1x=0.f, SP1y=0.f, SP1z=0.f, ap1x=0.f, ap1y=0.f, ap1z=0.f;

    const bool shared_xy = (cx0 == cx1) && (cy0 == cy1);   // wave-uniform

    if (shared_xy) {
        // One pass over the union box; every load serves both points.
        const int lox = clampc(cx0 - 1), hix = clampc(cx0 + 1);
        const int loy = clampc(cy0 - 1), hiy = clampc(cy0 + 1);
        const int loz = clampc(min(cz0, cz1) - 1), hiz = clampc(max(cz0, cz1) + 1);
        const int wy = hiy - loy + 1;
        const int npairs = (hix - lox + 1) * wy;           // <= 9
        int st_l = 0, en_l = 0;
        if (lane < npairs) {
            const int nx = lox + lane / wy;
            const int ny = loy + lane % wy;
            const int base = (nx * NC + ny) * NC;
            st_l = start[base + loz];
            en_l = start[base + hiz + 1];
        }
        for (int p = 0; p < npairs; ++p) {
            const int st = __shfl(st_l, p);
            const int en = __shfl(en_l, p);
            for (int j = st + lane; j < en; j += 64) {
                const float4 P = reinterpret_cast<const float4*>(pmP)[j];
                const float4 M = reinterpret_cast<const float4*>(pmM)[j];
                eval_one(P, M, x0, y0, z0, c0, px0, py0, pz0,
                         S0, SP0x, SP0y, SP0z, ap0x, ap0y, ap0z);
                eval_one(P, M, x1, y1, z1, c1, px1, py1, pz1,
                         S1, SP1x, SP1y, SP1z, ap1x, ap1y, ap1z);
            }
        }
    } else {
        // Two passes, each point its own 3x3 column set.
        #pragma unroll
        for (int pt = 0; pt < 2; ++pt) {
            const int cx = pt ? cx1 : cx0, cy = pt ? cy1 : cy0, cz = pt ? cz1 : cz0;
            const int lox = clampc(cx - 1), hix = clampc(cx + 1);
            const int loy = clampc(cy - 1), hiy = clampc(cy + 1);
            const int loz = clampc(cz - 1), hiz = clampc(cz + 1);
            const int wy = hiy - loy + 1;
            const int npairs = (hix - lox + 1) * wy;
            int st_l = 0, en_l = 0;
            if (lane < npairs) {
                const int nx = lox + lane / wy;
                const int ny = loy + lane % wy;
                const int base = (nx * NC + ny) * NC;
                st_l = start[base + loz];
                en_l = start[base + hiz + 1];
            }
            for (int p = 0; p < npairs; ++p) {
                const int st = __shfl(st_l, p);
                const int en = __shfl(en_l, p);
                for (int j = st + lane; j < en; j += 64) {
                    const float4 P = reinterpret_cast<const float4*>(pmP)[j];
                    const float4 M = reinterpret_cast<const float4*>(pmM)[j];
                    if (pt == 0)
                        eval_one(P, M, x0, y0, z0, c0, px0, py0, pz0,
                                 S0, SP0x, SP0y, SP0z, ap0x, ap0y, ap0z);
                    else
                        eval_one(P, M, x1, y1, z1, c1, px1, py1, pz1,
                                 S1, SP1x, SP1y, SP1z, ap1x, ap1y, ap1z);
                }
            }
        }
    }

    // 64-lane butterfly reduce of all 14 accumulators.
    #pragma unroll
    for (int off = 1; off < 64; off <<= 1) {
        S0   += __shfl_xor(S0,   off);
        SP0x += __shfl_xor(SP0x, off);
        SP0y += __shfl_xor(SP0y, off);
        SP0z += __shfl_xor(SP0z, off);
        ap0x += __shfl_xor(ap0x, off);
        ap0y += __shfl_xor(ap0y, off);
        ap0z += __shfl_xor(ap0z, off);
        S1   += __shfl_xor(S1,   off);
        SP1x += __shfl_xor(SP1x, off);
        SP1y += __shfl_xor(SP1y, off);
        SP1z += __shfl_xor(SP1z, off);
        ap1x += __shfl_xor(ap1x, off);
        ap1y += __shfl_xor(ap1y, off);
        ap1z += __shfl_xor(ap1z, off);
    }

    const float us = INV_SIG2 / A_DOT;
    if (lane == 0) {
        out[3*oi0+0] = INV_SIG2 * x0 * S0 - us * SP0x;
        out[3*oi0+1] = INV_SIG2 * y0 * S0 - us * SP0y;
        out[3*oi0+2] = INV_SIG2 * z0 * S0 - us * SP0z;
        out[3*NPTS + 3*oi0+0] = ap0x;
        out[3*NPTS + 3*oi0+1] = ap0y;
        out[3*NPTS + 3*oi0+2] = ap0z;
    } else if (lane == 1) {
        out[3*oi1+0] = INV_SIG2 * x1 * S1 - us * SP1x;
        out[3*oi1+1] = INV_SIG2 * y1 * S1 - us * SP1y;
        out[3*oi1+2] = INV_SIG2 * z1 * S1 - us * SP1z;
        out[3*NPTS + 3*oi1+0] = ap1x;
        out[3*NPTS + 3*oi1+1] = ap1y;
        out[3*NPTS + 3*oi1+2] = ap1z;
    }
}

extern "C" void kernel_launch(void* const* d_in, const int* in_sizes, int n_in,
                              void* d_out, int out_size, void* d_ws, size_t ws_size,
                              hipStream_t stream)
{
    const float* mom = (const float*)d_in[0];
    const float* pos = (const float*)d_in[1];
    float* out = (float*)d_out;

    // ws layout: pmP (4*NPTS f), pmM (4*NPTS f), inv (NPTS i), start (NCELL+1 i)
    float* pmP = (float*)d_ws;
    float* pmM = pmP + (size_t)4 * NPTS;
    int* inv   = (int*)(pmM + (size_t)4 * NPTS);
    int* start = inv + NPTS;

    k_prep<<<1, 1024, 0, stream>>>(mom, pos, pmP, pmM, inv, start);
    k_main<<<(NPTS / 2 * 64) / 256, 256, 0, stream>>>(mom, pos, pmP, pmM, inv, start, out);
}